// Round 1
// baseline (223.406 us; speedup 1.0000x reference)
//
#include <hip/hip_runtime.h>

typedef unsigned short u16;
typedef unsigned int u32;
typedef __bf16 bf16x8 __attribute__((ext_vector_type(8)));
typedef float f32x4 __attribute__((ext_vector_type(4)));

#define SCALE_QK 0.35355339059327373f  // 64^-0.25

__device__ __forceinline__ u16 f2bf(float f) {
  u32 u = __float_as_uint(f);
  u += 0x7FFFu + ((u >> 16) & 1u);
  return (u16)(u >> 16);
}

// ---------------- weight fp32 -> bf16 ----------------
__global__ __launch_bounds__(256) void k_convert(const float* __restrict__ src,
                                                 u16* __restrict__ dst, int n4) {
  int i = blockIdx.x * 256 + threadIdx.x;
  if (i >= n4) return;
  float4 v = ((const float4*)src)[i];
  u32 lo = (u32)f2bf(v.x) | ((u32)f2bf(v.y) << 16);
  u32 hi = (u32)f2bf(v.z) | ((u32)f2bf(v.w) << 16);
  ((uint2*)dst)[i] = make_uint2(lo, hi);
}

// ---------------- fused GroupNorm: block = (b,g); writes gn_t[b][t][c] bf16 ----------------
__global__ __launch_bounds__(256) void k_groupnorm(const float* __restrict__ x,
                                                   const float* __restrict__ nw,
                                                   const float* __restrict__ nb,
                                                   u16* __restrict__ gnt) {
  const int b = blockIdx.x >> 5;
  const int g = blockIdx.x & 31;
  const int tid = threadIdx.x;
  const float* xg = x + ((size_t)b * 512 + g * 16) * 1024;

  float s = 0.f, ss = 0.f;
#pragma unroll
  for (int it = 0; it < 16; ++it) {
    float4 v = ((const float4*)xg)[tid + it * 256];
    s += v.x + v.y + v.z + v.w;
    ss += v.x * v.x + v.y * v.y + v.z * v.z + v.w * v.w;
  }
#pragma unroll
  for (int off = 32; off >= 1; off >>= 1) {
    s += __shfl_xor(s, off);
    ss += __shfl_xor(ss, off);
  }
  __shared__ float red[8];
  const int wid = tid >> 6, lane = tid & 63;
  if (lane == 0) { red[wid] = s; red[4 + wid] = ss; }
  __syncthreads();
  const float mean = (red[0] + red[1] + red[2] + red[3]) * (1.f / 16384.f);
  const float ex2 = (red[4] + red[5] + red[6] + red[7]) * (1.f / 16384.f);
  const float rstd = rsqrtf(ex2 - mean * mean + 1e-5f);

  const int ci = tid & 15, tt = tid >> 4;
  const int c = g * 16 + ci;
  const float wc = nw[c] * rstd;
  const float bc = nb[c] - mean * wc;
  const float* xc = xg + (size_t)ci * 1024;
  u16* dst = gnt + (size_t)b * 1024 * 512 + c;
#pragma unroll 8
  for (int t = tt; t < 1024; t += 16) {
    dst[(size_t)t * 512] = f2bf(xc[t] * wc + bc);
  }
}

// ---------------- GEMM: D[(b,t)][o] = sum_c A[(b,t)][c] * Bw[o][c]  (K=512) ----------------
// MODE 0: A=gn_t, Bw=qkv_w -> scatter Q/K/V (scale folded into Q,K)
// MODE 1: A=h_t, Bw=proj_w -> out = D + bias + x (fp32)
template <int MODE>
__global__ __launch_bounds__(256) void k_gemm(const u16* __restrict__ A,
                                              const u16* __restrict__ Bw,
                                              const float* __restrict__ bias,
                                              u16* __restrict__ Qb, u16* __restrict__ Kb,
                                              u16* __restrict__ Vb,
                                              const float* __restrict__ xres,
                                              float* __restrict__ out) {
  __shared__ u16 As[128][64];
  __shared__ u16 Bs[128][64];
  const int tid = threadIdx.x;
  const int lane = tid & 63, wid = tid >> 6;
  const int wr = wid >> 1, wc = wid & 1;
  const int m0 = blockIdx.y * 128;
  const int n0 = blockIdx.x * 128;
  const int l15 = lane & 15, l4 = lane >> 4;
  const f32x4 fzero = {0.f, 0.f, 0.f, 0.f};

  f32x4 acc[4][4];
#pragma unroll
  for (int i = 0; i < 4; ++i)
#pragma unroll
    for (int j = 0; j < 4; ++j) acc[i][j] = fzero;

  for (int kt = 0; kt < 8; ++kt) {
    __syncthreads();
#pragma unroll
    for (int i = 0; i < 4; ++i) {
      const int idx = tid + i * 256;
      const int r = idx >> 3, c8 = idx & 7;
      const int sw = (c8 ^ (r & 7)) * 8;
      *(uint4*)&As[r][sw] = *(const uint4*)(A + ((size_t)(m0 + r) * 512 + kt * 64 + c8 * 8));
      *(uint4*)&Bs[r][sw] = *(const uint4*)(Bw + ((size_t)(n0 + r) * 512 + kt * 64 + c8 * 8));
    }
    __syncthreads();
#pragma unroll
    for (int ks = 0; ks < 2; ++ks) {
      bf16x8 af[4], bfr[4];
#pragma unroll
      for (int mi = 0; mi < 4; ++mi) {
        const int row = wr * 64 + mi * 16 + l15;
        af[mi] = *(const bf16x8*)&As[row][(((ks << 2) + l4) ^ (row & 7)) << 3];
      }
#pragma unroll
      for (int ni = 0; ni < 4; ++ni) {
        const int row = wc * 64 + ni * 16 + l15;
        bfr[ni] = *(const bf16x8*)&Bs[row][(((ks << 2) + l4) ^ (row & 7)) << 3];
      }
#pragma unroll
      for (int mi = 0; mi < 4; ++mi)
#pragma unroll
        for (int ni = 0; ni < 4; ++ni)
          acc[mi][ni] = __builtin_amdgcn_mfma_f32_16x16x32_bf16(af[mi], bfr[ni], acc[mi][ni], 0, 0, 0);
    }
  }

#pragma unroll
  for (int ni = 0; ni < 4; ++ni) {
    const int o = n0 + wc * 64 + ni * 16 + l15;
    const float bo = bias[o];
    if (MODE == 0) {
      const int h = o / 192;
      const int jo = o - h * 192;
      const int typ = jo >> 6;  // 0=q 1=k 2=v
      const int ci = jo & 63;
#pragma unroll
      for (int mi = 0; mi < 4; ++mi) {
        const int mrow = m0 + wr * 64 + mi * 16 + l4 * 4;
        const int b = mrow >> 10, t0 = mrow & 1023;
#pragma unroll
        for (int jj = 0; jj < 4; ++jj) {
          const float v = acc[mi][ni][jj] + bo;
          const int t = t0 + jj;
          if (typ == 0)
            Qb[(((size_t)(b * 8 + h) * 1024 + t) << 6) + ci] = f2bf(v * SCALE_QK);
          else if (typ == 1)
            Kb[(((size_t)(b * 8 + h) * 1024 + t) << 6) + ci] = f2bf(v * SCALE_QK);
          else
            Vb[(((size_t)(b * 8 + h) * 64 + ci) << 10) + t] = f2bf(v);
        }
      }
    } else {
#pragma unroll
      for (int mi = 0; mi < 4; ++mi) {
        const int mrow = m0 + wr * 64 + mi * 16 + l4 * 4;
        const int b = mrow >> 10, t0 = mrow & 1023;
        const size_t base = ((size_t)b * 512 + o) * 1024 + t0;
        const float4 xr = *(const float4*)(xres + base);
        float4 ov;
        ov.x = acc[mi][ni][0] + bo + xr.x;
        ov.y = acc[mi][ni][1] + bo + xr.y;
        ov.z = acc[mi][ni][2] + bo + xr.z;
        ov.w = acc[mi][ni][3] + bo + xr.w;
        *(float4*)(out + base) = ov;
      }
    }
  }
}

// ---------------- flash attention: block = (bh, qtile of 64 rows), 4 waves x 16 rows ----------------
__global__ __launch_bounds__(256) void k_attn(const u16* __restrict__ Qb,
                                              const u16* __restrict__ Kb,
                                              const u16* __restrict__ Vb,
                                              u16* __restrict__ ht) {
  __shared__ u16 Ks[64][64];      // [s][c] swizzled
  __shared__ u16 Vs[64][64];      // [c][s] swizzled
  __shared__ u16 Ps[4][16][64];   // per-wave P [t][s] swizzled
  const int tid = threadIdx.x;
  const int lane = tid & 63, wid = tid >> 6;
  const int l15 = lane & 15, l4 = lane >> 4;
  const int bh = blockIdx.y, qt = blockIdx.x;
  const int b = bh >> 3, head = bh & 7;
  const f32x4 fzero = {0.f, 0.f, 0.f, 0.f};

  bf16x8 qa[2];
  {
    const u16* qp = Qb + (((size_t)bh * 1024 + qt * 64 + wid * 16 + l15) << 6) + l4 * 8;
    qa[0] = *(const bf16x8*)qp;
    qa[1] = *(const bf16x8*)(qp + 32);
  }

  f32x4 oacc[4];
#pragma unroll
  for (int i = 0; i < 4; ++i) oacc[i] = fzero;
  float m[4] = {-1e30f, -1e30f, -1e30f, -1e30f};
  float lsum[4] = {0.f, 0.f, 0.f, 0.f};

  for (int st = 0; st < 16; ++st) {
    const int s0 = st * 64;
    __syncthreads();
#pragma unroll
    for (int i = 0; i < 2; ++i) {
      const int idx = tid + i * 256;
      const int r = idx >> 3, c8 = idx & 7;
      const int sw = (c8 ^ (r & 7)) * 8;
      *(uint4*)&Ks[r][sw] = *(const uint4*)(Kb + (((size_t)bh * 1024 + s0 + r) << 6) + c8 * 8);
      *(uint4*)&Vs[r][sw] = *(const uint4*)(Vb + (((size_t)bh * 64 + r) << 10) + s0 + c8 * 8);
    }
    __syncthreads();

    f32x4 sacc[4];
#pragma unroll
    for (int i = 0; i < 4; ++i) sacc[i] = fzero;
#pragma unroll
    for (int ks = 0; ks < 2; ++ks) {
#pragma unroll
      for (int si = 0; si < 4; ++si) {
        const int row = si * 16 + l15;
        const bf16x8 kb = *(const bf16x8*)&Ks[row][(((ks << 2) + l4) ^ (row & 7)) << 3];
        sacc[si] = __builtin_amdgcn_mfma_f32_16x16x32_bf16(qa[ks], kb, sacc[si], 0, 0, 0);
      }
    }

#pragma unroll
    for (int j = 0; j < 4; ++j) {
      float mx = fmaxf(fmaxf(sacc[0][j], sacc[1][j]), fmaxf(sacc[2][j], sacc[3][j]));
      mx = fmaxf(mx, __shfl_xor(mx, 1));
      mx = fmaxf(mx, __shfl_xor(mx, 2));
      mx = fmaxf(mx, __shfl_xor(mx, 4));
      mx = fmaxf(mx, __shfl_xor(mx, 8));
      const float nm = fmaxf(m[j], mx);
      const float sc = __expf(m[j] - nm);
      m[j] = nm;
      const float p0 = __expf(sacc[0][j] - nm);
      const float p1 = __expf(sacc[1][j] - nm);
      const float p2 = __expf(sacc[2][j] - nm);
      const float p3 = __expf(sacc[3][j] - nm);
      float rs = p0 + p1 + p2 + p3;
      rs += __shfl_xor(rs, 1);
      rs += __shfl_xor(rs, 2);
      rs += __shfl_xor(rs, 4);
      rs += __shfl_xor(rs, 8);
      lsum[j] = lsum[j] * sc + rs;
#pragma unroll
      for (int ni = 0; ni < 4; ++ni) oacc[ni][j] *= sc;
      const int t = l4 * 4 + j;
      const int swz = (t & 7) << 3;
      Ps[wid][t][(0 + l15) ^ swz] = f2bf(p0);
      Ps[wid][t][(16 + l15) ^ swz] = f2bf(p1);
      Ps[wid][t][(32 + l15) ^ swz] = f2bf(p2);
      Ps[wid][t][(48 + l15) ^ swz] = f2bf(p3);
    }

#pragma unroll
    for (int ks = 0; ks < 2; ++ks) {
      const bf16x8 pa = *(const bf16x8*)&Ps[wid][l15][(((ks << 2) + l4) ^ (l15 & 7)) << 3];
#pragma unroll
      for (int ni = 0; ni < 4; ++ni) {
        const int row = ni * 16 + l15;
        const bf16x8 vb = *(const bf16x8*)&Vs[row][(((ks << 2) + l4) ^ (row & 7)) << 3];
        oacc[ni] = __builtin_amdgcn_mfma_f32_16x16x32_bf16(pa, vb, oacc[ni], 0, 0, 0);
      }
    }
  }

  const int t0 = qt * 64 + wid * 16 + l4 * 4;
  float inv[4];
#pragma unroll
  for (int j = 0; j < 4; ++j) inv[j] = 1.f / lsum[j];
#pragma unroll
  for (int ni = 0; ni < 4; ++ni) {
    const int cg = head * 64 + ni * 16 + l15;
#pragma unroll
    for (int j = 0; j < 4; ++j) {
      ht[((size_t)b * 1024 + t0 + j) * 512 + cg] = f2bf(oacc[ni][j] * inv[j]);
    }
  }
}

extern "C" void kernel_launch(void* const* d_in, const int* in_sizes, int n_in,
                              void* d_out, int out_size, void* d_ws, size_t ws_size,
                              hipStream_t stream) {
  const float* x = (const float*)d_in[0];
  const float* norm_w = (const float*)d_in[1];
  const float* norm_b = (const float*)d_in[2];
  const float* qkv_w = (const float*)d_in[3];
  const float* qkv_b = (const float*)d_in[4];
  const float* proj_w = (const float*)d_in[5];
  const float* proj_b = (const float*)d_in[6];
  float* out = (float*)d_out;

  char* ws = (char*)d_ws;
  u16* qkvw = (u16*)(ws + 0);          // 1,572,864 B
  u16* projw = (u16*)(ws + 1572864);   //   524,288 B
  u16* gnt = (u16*)(ws + 2097152);     // 16,777,216 B  gn_t[b][t][c]
  u16* Qb = (u16*)(ws + 18874368);     // 16,777,216 B  Q[bh][t][ci]
  u16* Kb = (u16*)(ws + 35651584);     // 16,777,216 B  K[bh][s][ci]
  u16* Vb = (u16*)(ws + 52428800);     // 16,777,216 B  V[bh][ci][s]
  u16* ht = (u16*)(ws + 69206016);     // 16,777,216 B  h_t[b][t][c]

  k_convert<<<768, 256, 0, stream>>>(qkv_w, qkvw, 196608);
  k_convert<<<256, 256, 0, stream>>>(proj_w, projw, 65536);
  k_groupnorm<<<512, 256, 0, stream>>>(x, norm_w, norm_b, gnt);
  k_gemm<0><<<dim3(12, 128), 256, 0, stream>>>(gnt, qkvw, qkv_b, Qb, Kb, Vb, nullptr, nullptr);
  k_attn<<<dim3(16, 128), 256, 0, stream>>>(Qb, Kb, Vb, ht);
  k_gemm<1><<<dim3(4, 128), 256, 0, stream>>>(ht, projw, proj_b, nullptr, nullptr, nullptr, x, out);
}

// Round 2
// 178.198 us; speedup vs baseline: 1.2537x; 1.2537x over previous
//
#include <hip/hip_runtime.h>

typedef unsigned short u16;
typedef unsigned int u32;
typedef __bf16 bf16x8 __attribute__((ext_vector_type(8)));
typedef float f32x4 __attribute__((ext_vector_type(4)));

#define SCALE_QK 0.35355339059327373f  // 64^-0.25
#define LOG2E 1.4426950408889634f

__device__ __forceinline__ u16 f2bf(float f) {
  u32 u = __float_as_uint(f);
  u += 0x7FFFu + ((u >> 16) & 1u);
  return (u16)(u >> 16);
}

__device__ __forceinline__ void gload16(const u16* g, u16* l) {
  __builtin_amdgcn_global_load_lds((const __attribute__((address_space(1))) void*)g,
                                   (__attribute__((address_space(3))) void*)l, 16, 0, 0);
}

// ---------------- weight fp32 -> bf16 ----------------
__global__ __launch_bounds__(256) void k_convert(const float* __restrict__ src,
                                                 u16* __restrict__ dst, int n4) {
  int i = blockIdx.x * 256 + threadIdx.x;
  if (i >= n4) return;
  float4 v = ((const float4*)src)[i];
  u32 lo = (u32)f2bf(v.x) | ((u32)f2bf(v.y) << 16);
  u32 hi = (u32)f2bf(v.z) | ((u32)f2bf(v.w) << 16);
  ((uint2*)dst)[i] = make_uint2(lo, hi);
}

// ---------------- fused GroupNorm: block = (b,g); writes gn_t[b][t][c] bf16 ----------------
__global__ __launch_bounds__(256) void k_groupnorm(const float* __restrict__ x,
                                                   const float* __restrict__ nw,
                                                   const float* __restrict__ nb,
                                                   u16* __restrict__ gnt) {
  const int b = blockIdx.x >> 5;
  const int g = blockIdx.x & 31;
  const int tid = threadIdx.x;
  const float* xg = x + ((size_t)b * 512 + g * 16) * 1024;

  float s = 0.f, ss = 0.f;
#pragma unroll
  for (int it = 0; it < 16; ++it) {
    float4 v = ((const float4*)xg)[tid + it * 256];
    s += v.x + v.y + v.z + v.w;
    ss += v.x * v.x + v.y * v.y + v.z * v.z + v.w * v.w;
  }
#pragma unroll
  for (int off = 32; off >= 1; off >>= 1) {
    s += __shfl_xor(s, off);
    ss += __shfl_xor(ss, off);
  }
  __shared__ float red[8];
  const int wid = tid >> 6, lane = tid & 63;
  if (lane == 0) { red[wid] = s; red[4 + wid] = ss; }
  __syncthreads();
  const float mean = (red[0] + red[1] + red[2] + red[3]) * (1.f / 16384.f);
  const float ex2 = (red[4] + red[5] + red[6] + red[7]) * (1.f / 16384.f);
  const float rstd = rsqrtf(ex2 - mean * mean + 1e-5f);

  const int ci = tid & 15, tt = tid >> 4;
  const int c = g * 16 + ci;
  const float wc = nw[c] * rstd;
  const float bc = nb[c] - mean * wc;
  const float* xc = xg + (size_t)ci * 1024;
  u16* dst = gnt + (size_t)b * 1024 * 512 + c;
#pragma unroll 8
  for (int t = tt; t < 1024; t += 16) {
    dst[(size_t)t * 512] = f2bf(xc[t] * wc + bc);
  }
}

// ---------------- GEMM: D[(b,t)][o] = sum_c A[(b,t)][c] * Bw[o][c]  (K=512) ----------------
// MODE 0: A=gn_t, Bw=qkv_w -> scatter Q/K/V (scale folded into Q,K; log2e folded into Q)
// MODE 1: A=h_t, Bw=proj_w -> out = D + bias + x (fp32)
template <int MODE>
__global__ __launch_bounds__(256) void k_gemm(const u16* __restrict__ A,
                                              const u16* __restrict__ Bw,
                                              const float* __restrict__ bias,
                                              u16* __restrict__ Qb, u16* __restrict__ Kb,
                                              u16* __restrict__ Vb,
                                              const float* __restrict__ xres,
                                              float* __restrict__ out) {
  __shared__ u16 As[128][64];
  __shared__ u16 Bs[128][64];
  const int tid = threadIdx.x;
  const int lane = tid & 63, wid = tid >> 6;
  const int wr = wid >> 1, wc = wid & 1;
  const int m0 = blockIdx.y * 128;
  const int n0 = blockIdx.x * 128;
  const int l15 = lane & 15, l4 = lane >> 4;
  const f32x4 fzero = {0.f, 0.f, 0.f, 0.f};

  f32x4 acc[4][4];
#pragma unroll
  for (int i = 0; i < 4; ++i)
#pragma unroll
    for (int j = 0; j < 4; ++j) acc[i][j] = fzero;

  const int lrow = lane >> 3;          // 0..7 within wave's 8-row slab
  const int lchunk = lane & 7;         // 16B chunk within row

  for (int kt = 0; kt < 8; ++kt) {
    __syncthreads();
#pragma unroll
    for (int rd = 0; rd < 4; ++rd) {
      const int rbase = wid * 8 + rd * 32;
      const int r = rbase + lrow;
      const int q = lchunk ^ (r & 7);
      gload16(A + ((size_t)(m0 + r) * 512 + kt * 64 + q * 8), &As[rbase][0]);
      gload16(Bw + ((size_t)(n0 + r) * 512 + kt * 64 + q * 8), &Bs[rbase][0]);
    }
    __syncthreads();
#pragma unroll
    for (int ks = 0; ks < 2; ++ks) {
      bf16x8 af[4], bfr[4];
#pragma unroll
      for (int mi = 0; mi < 4; ++mi) {
        const int row = wr * 64 + mi * 16 + l15;
        af[mi] = *(const bf16x8*)&As[row][(((ks << 2) + l4) ^ (row & 7)) << 3];
      }
#pragma unroll
      for (int ni = 0; ni < 4; ++ni) {
        const int row = wc * 64 + ni * 16 + l15;
        bfr[ni] = *(const bf16x8*)&Bs[row][(((ks << 2) + l4) ^ (row & 7)) << 3];
      }
#pragma unroll
      for (int mi = 0; mi < 4; ++mi)
#pragma unroll
        for (int ni = 0; ni < 4; ++ni)
          acc[mi][ni] = __builtin_amdgcn_mfma_f32_16x16x32_bf16(af[mi], bfr[ni], acc[mi][ni], 0, 0, 0);
    }
  }

#pragma unroll
  for (int ni = 0; ni < 4; ++ni) {
    const int o = n0 + wc * 64 + ni * 16 + l15;
    const float bo = bias[o];
    if (MODE == 0) {
      const int h = o / 192;
      const int jo = o - h * 192;
      const int typ = jo >> 6;  // 0=q 1=k 2=v
      const int ci = jo & 63;
#pragma unroll
      for (int mi = 0; mi < 4; ++mi) {
        const int mrow = m0 + wr * 64 + mi * 16 + l4 * 4;
        const int b = mrow >> 10, t0 = mrow & 1023;
#pragma unroll
        for (int jj = 0; jj < 4; ++jj) {
          const float v = acc[mi][ni][jj] + bo;
          const int t = t0 + jj;
          if (typ == 0)
            Qb[(((size_t)(b * 8 + h) * 1024 + t) << 6) + ci] = f2bf(v * (SCALE_QK * LOG2E));
          else if (typ == 1)
            Kb[(((size_t)(b * 8 + h) * 1024 + t) << 6) + ci] = f2bf(v * SCALE_QK);
          else
            Vb[(((size_t)(b * 8 + h) * 64 + ci) << 10) + t] = f2bf(v);
        }
      }
    } else {
#pragma unroll
      for (int mi = 0; mi < 4; ++mi) {
        const int mrow = m0 + wr * 64 + mi * 16 + l4 * 4;
        const int b = mrow >> 10, t0 = mrow & 1023;
        const size_t base = ((size_t)b * 512 + o) * 1024 + t0;
        const float4 xr = *(const float4*)(xres + base);
        float4 ov;
        ov.x = acc[mi][ni][0] + bo + xr.x;
        ov.y = acc[mi][ni][1] + bo + xr.y;
        ov.z = acc[mi][ni][2] + bo + xr.z;
        ov.w = acc[mi][ni][3] + bo + xr.w;
        *(float4*)(out + base) = ov;
      }
    }
  }
}

// ---------------- flash attention, exp-only softmax (no running max) ----------------
// P = exp2(s) with log2e pre-folded into Q; row-sum via MFMA ones-column; normalize at end.
__global__ __launch_bounds__(256) void k_attn(const u16* __restrict__ Qb,
                                              const u16* __restrict__ Kb,
                                              const u16* __restrict__ Vb,
                                              u16* __restrict__ ht) {
  __shared__ u16 Ks[2][64][64];   // [s][c] swizzled
  __shared__ u16 Vs[2][64][64];   // [c][s] swizzled
  __shared__ u16 Ps[4][16][64];   // per-wave P [t][s] swizzled
  const int tid = threadIdx.x;
  const int lane = tid & 63, wid = tid >> 6;
  const int l15 = lane & 15, l4 = lane >> 4;
  const int bh = blockIdx.y, qt = blockIdx.x;
  const int b = bh >> 3, head = bh & 7;
  const f32x4 fzero = {0.f, 0.f, 0.f, 0.f};
  const int lrow = lane >> 3, lchunk = lane & 7;

  bf16x8 qa[2];
  {
    const u16* qp = Qb + (((size_t)bh * 1024 + qt * 64 + wid * 16 + l15) << 6) + l4 * 8;
    qa[0] = *(const bf16x8*)qp;
    qa[1] = *(const bf16x8*)(qp + 32);
  }

  // ones B-fragment: B[k][col] = (col==0) ? 1 : 0  -> D col 0 = row sums
  bf16x8 onesf;
#pragma unroll
  for (int i = 0; i < 8; ++i) onesf[i] = (l15 == 0) ? (__bf16)1.0f : (__bf16)0.0f;

  f32x4 oacc[5];
#pragma unroll
  for (int i = 0; i < 5; ++i) oacc[i] = fzero;

  auto stageKV = [&](int bi, int st) {
    const int s0 = st * 64;
#pragma unroll
    for (int rd = 0; rd < 2; ++rd) {
      const int rbase = wid * 8 + rd * 32;
      const int r = rbase + lrow;
      const int q = lchunk ^ (r & 7);
      gload16(Kb + (((size_t)bh * 1024 + s0 + r) << 6) + q * 8, &Ks[bi][rbase][0]);
      gload16(Vb + (((size_t)bh * 64 + r) << 10) + s0 + q * 8, &Vs[bi][rbase][0]);
    }
  };

  stageKV(0, 0);
  asm volatile("s_waitcnt vmcnt(0)" ::: "memory");
  __builtin_amdgcn_s_barrier();

  int buf = 0;
  for (int st = 0; st < 16; ++st) {
    if (st < 15) stageKV(buf ^ 1, st + 1);

    // QK^T: sacc[si][j] = S[t = l4*4+j][s = si*16 + l15] (times log2e)
    f32x4 sacc[4];
#pragma unroll
    for (int i = 0; i < 4; ++i) sacc[i] = fzero;
#pragma unroll
    for (int ks = 0; ks < 2; ++ks) {
#pragma unroll
      for (int si = 0; si < 4; ++si) {
        const int row = si * 16 + l15;
        const bf16x8 kb = *(const bf16x8*)&Ks[buf][row][(((ks << 2) + l4) ^ (row & 7)) << 3];
        sacc[si] = __builtin_amdgcn_mfma_f32_16x16x32_bf16(qa[ks], kb, sacc[si], 0, 0, 0);
      }
    }

    // P = 2^sacc, pack to bf16, store to per-wave LDS
#pragma unroll
    for (int j = 0; j < 4; ++j) {
      float e0, e1, e2, e3;
      asm("v_exp_f32 %0, %1" : "=v"(e0) : "v"(sacc[0][j]));
      asm("v_exp_f32 %0, %1" : "=v"(e1) : "v"(sacc[1][j]));
      asm("v_exp_f32 %0, %1" : "=v"(e2) : "v"(sacc[2][j]));
      asm("v_exp_f32 %0, %1" : "=v"(e3) : "v"(sacc[3][j]));
      u32 pk01, pk23;
      asm("v_cvt_pk_bf16_f32 %0, %1, %2" : "=v"(pk01) : "v"(e0), "v"(e1));
      asm("v_cvt_pk_bf16_f32 %0, %1, %2" : "=v"(pk23) : "v"(e2), "v"(e3));
      const int t = l4 * 4 + j;
      const int swz = (t & 7) << 3;
      u16* pr = &Ps[wid][t][0];
      pr[(l15) ^ swz] = (u16)pk01;
      pr[(16 + l15) ^ swz] = (u16)(pk01 >> 16);
      pr[(32 + l15) ^ swz] = (u16)pk23;
      pr[(48 + l15) ^ swz] = (u16)(pk23 >> 16);
    }

    // PV (+ ones-column row-sum in oacc[4])
#pragma unroll
    for (int ks = 0; ks < 2; ++ks) {
      const bf16x8 pa = *(const bf16x8*)&Ps[wid][l15][(((ks << 2) + l4) ^ (l15 & 7)) << 3];
#pragma unroll
      for (int ni = 0; ni < 4; ++ni) {
        const int row = ni * 16 + l15;
        const bf16x8 vb = *(const bf16x8*)&Vs[buf][row][(((ks << 2) + l4) ^ (row & 7)) << 3];
        oacc[ni] = __builtin_amdgcn_mfma_f32_16x16x32_bf16(pa, vb, oacc[ni], 0, 0, 0);
      }
      oacc[4] = __builtin_amdgcn_mfma_f32_16x16x32_bf16(pa, onesf, oacc[4], 0, 0, 0);
    }

    asm volatile("s_waitcnt vmcnt(0)" ::: "memory");
    __builtin_amdgcn_s_barrier();
    buf ^= 1;
  }

  const int t0 = qt * 64 + wid * 16 + l4 * 4;
  float inv[4];
#pragma unroll
  for (int j = 0; j < 4; ++j) {
    const float ls = __shfl(oacc[4][j], lane & 48);  // broadcast from l15==0 lane
    inv[j] = 1.f / ls;
  }
#pragma unroll
  for (int ni = 0; ni < 4; ++ni) {
    const int cg = head * 64 + ni * 16 + l15;
#pragma unroll
    for (int j = 0; j < 4; ++j) {
      ht[((size_t)b * 1024 + t0 + j) * 512 + cg] = f2bf(oacc[ni][j] * inv[j]);
    }
  }
}

extern "C" void kernel_launch(void* const* d_in, const int* in_sizes, int n_in,
                              void* d_out, int out_size, void* d_ws, size_t ws_size,
                              hipStream_t stream) {
  const float* x = (const float*)d_in[0];
  const float* norm_w = (const float*)d_in[1];
  const float* norm_b = (const float*)d_in[2];
  const float* qkv_w = (const float*)d_in[3];
  const float* qkv_b = (const float*)d_in[4];
  const float* proj_w = (const float*)d_in[5];
  const float* proj_b = (const float*)d_in[6];
  float* out = (float*)d_out;

  char* ws = (char*)d_ws;
  u16* qkvw = (u16*)(ws + 0);          // 1,572,864 B
  u16* projw = (u16*)(ws + 1572864);   //   524,288 B
  u16* gnt = (u16*)(ws + 2097152);     // 16,777,216 B  gn_t[b][t][c]
  u16* Qb = (u16*)(ws + 18874368);     // 16,777,216 B  Q[bh][t][ci]
  u16* Kb = (u16*)(ws + 35651584);     // 16,777,216 B  K[bh][s][ci]
  u16* Vb = (u16*)(ws + 52428800);     // 16,777,216 B  V[bh][ci][s]
  u16* ht = (u16*)(ws + 69206016);     // 16,777,216 B  h_t[b][t][c]

  k_convert<<<768, 256, 0, stream>>>(qkv_w, qkvw, 196608);
  k_convert<<<256, 256, 0, stream>>>(proj_w, projw, 65536);
  k_groupnorm<<<512, 256, 0, stream>>>(x, norm_w, norm_b, gnt);
  k_gemm<0><<<dim3(12, 128), 256, 0, stream>>>(gnt, qkvw, qkv_b, Qb, Kb, Vb, nullptr, nullptr);
  k_attn<<<dim3(16, 128), 256, 0, stream>>>(Qb, Kb, Vb, ht);
  k_gemm<1><<<dim3(4, 128), 256, 0, stream>>>(ht, projw, proj_b, nullptr, nullptr, nullptr, x, out);
}

// Round 3
// 172.333 us; speedup vs baseline: 1.2964x; 1.0340x over previous
//
#include <hip/hip_runtime.h>

typedef unsigned short u16;
typedef unsigned int u32;
typedef __bf16 bf16x8 __attribute__((ext_vector_type(8)));
typedef float f32x4 __attribute__((ext_vector_type(4)));
typedef float f32x16 __attribute__((ext_vector_type(16)));

#define SCALE_QK 0.35355339059327373f  // 64^-0.25
#define LOG2E 1.4426950408889634f

__device__ __forceinline__ u16 f2bf(float f) {
  u32 u = __float_as_uint(f);
  u += 0x7FFFu + ((u >> 16) & 1u);
  return (u16)(u >> 16);
}

__device__ __forceinline__ void gload16(const u16* g, u16* l) {
  __builtin_amdgcn_global_load_lds((const __attribute__((address_space(1))) void*)g,
                                   (__attribute__((address_space(3))) void*)l, 16, 0, 0);
}

// ---------------- weight fp32 -> bf16 ----------------
__global__ __launch_bounds__(256) void k_convert(const float* __restrict__ src,
                                                 u16* __restrict__ dst, int n4) {
  int i = blockIdx.x * 256 + threadIdx.x;
  if (i >= n4) return;
  float4 v = ((const float4*)src)[i];
  u32 lo = (u32)f2bf(v.x) | ((u32)f2bf(v.y) << 16);
  u32 hi = (u32)f2bf(v.z) | ((u32)f2bf(v.w) << 16);
  ((uint2*)dst)[i] = make_uint2(lo, hi);
}

// ---------------- fused GroupNorm: block = (b,g); writes gn_t[b][t][c] bf16 ----------------
__global__ __launch_bounds__(256) void k_groupnorm(const float* __restrict__ x,
                                                   const float* __restrict__ nw,
                                                   const float* __restrict__ nb,
                                                   u16* __restrict__ gnt) {
  const int b = blockIdx.x >> 5;
  const int g = blockIdx.x & 31;
  const int tid = threadIdx.x;
  const float* xg = x + ((size_t)b * 512 + g * 16) * 1024;

  float s = 0.f, ss = 0.f;
#pragma unroll
  for (int it = 0; it < 16; ++it) {
    float4 v = ((const float4*)xg)[tid + it * 256];
    s += v.x + v.y + v.z + v.w;
    ss += v.x * v.x + v.y * v.y + v.z * v.z + v.w * v.w;
  }
#pragma unroll
  for (int off = 32; off >= 1; off >>= 1) {
    s += __shfl_xor(s, off);
    ss += __shfl_xor(ss, off);
  }
  __shared__ float red[8];
  const int wid = tid >> 6, lane = tid & 63;
  if (lane == 0) { red[wid] = s; red[4 + wid] = ss; }
  __syncthreads();
  const float mean = (red[0] + red[1] + red[2] + red[3]) * (1.f / 16384.f);
  const float ex2 = (red[4] + red[5] + red[6] + red[7]) * (1.f / 16384.f);
  const float rstd = rsqrtf(ex2 - mean * mean + 1e-5f);

  const int ci = tid & 15, tt = tid >> 4;
  const int c = g * 16 + ci;
  const float wc = nw[c] * rstd;
  const float bc = nb[c] - mean * wc;
  const float* xc = xg + (size_t)ci * 1024;
  u16* dst = gnt + (size_t)b * 1024 * 512 + c;
#pragma unroll 8
  for (int t = tt; t < 1024; t += 16) {
    dst[(size_t)t * 512] = f2bf(xc[t] * wc + bc);
  }
}

// ---------------- GEMM: D[(b,t)][o] = sum_c A[(b,t)][c] * Bw[o][c]  (K=512) ----------------
template <int MODE>
__global__ __launch_bounds__(256) void k_gemm(const u16* __restrict__ A,
                                              const u16* __restrict__ Bw,
                                              const float* __restrict__ bias,
                                              u16* __restrict__ Qb, u16* __restrict__ Kb,
                                              u16* __restrict__ Vb,
                                              const float* __restrict__ xres,
                                              float* __restrict__ out) {
  __shared__ u16 As[128][64];
  __shared__ u16 Bs[128][64];
  const int tid = threadIdx.x;
  const int lane = tid & 63, wid = tid >> 6;
  const int wr = wid >> 1, wc = wid & 1;
  const int m0 = blockIdx.y * 128;
  const int n0 = blockIdx.x * 128;
  const int l15 = lane & 15, l4 = lane >> 4;
  const f32x4 fzero = {0.f, 0.f, 0.f, 0.f};

  f32x4 acc[4][4];
#pragma unroll
  for (int i = 0; i < 4; ++i)
#pragma unroll
    for (int j = 0; j < 4; ++j) acc[i][j] = fzero;

  const int lrow = lane >> 3;
  const int lchunk = lane & 7;

  for (int kt = 0; kt < 8; ++kt) {
    __syncthreads();
#pragma unroll
    for (int rd = 0; rd < 4; ++rd) {
      const int rbase = wid * 8 + rd * 32;
      const int r = rbase + lrow;
      const int q = lchunk ^ (r & 7);
      gload16(A + ((size_t)(m0 + r) * 512 + kt * 64 + q * 8), &As[rbase][0]);
      gload16(Bw + ((size_t)(n0 + r) * 512 + kt * 64 + q * 8), &Bs[rbase][0]);
    }
    __syncthreads();
#pragma unroll
    for (int ks = 0; ks < 2; ++ks) {
      bf16x8 af[4], bfr[4];
#pragma unroll
      for (int mi = 0; mi < 4; ++mi) {
        const int row = wr * 64 + mi * 16 + l15;
        af[mi] = *(const bf16x8*)&As[row][(((ks << 2) + l4) ^ (row & 7)) << 3];
      }
#pragma unroll
      for (int ni = 0; ni < 4; ++ni) {
        const int row = wc * 64 + ni * 16 + l15;
        bfr[ni] = *(const bf16x8*)&Bs[row][(((ks << 2) + l4) ^ (row & 7)) << 3];
      }
#pragma unroll
      for (int mi = 0; mi < 4; ++mi)
#pragma unroll
        for (int ni = 0; ni < 4; ++ni)
          acc[mi][ni] = __builtin_amdgcn_mfma_f32_16x16x32_bf16(af[mi], bfr[ni], acc[mi][ni], 0, 0, 0);
    }
  }

#pragma unroll
  for (int ni = 0; ni < 4; ++ni) {
    const int o = n0 + wc * 64 + ni * 16 + l15;
    const float bo = bias[o];
    if (MODE == 0) {
      const int h = o / 192;
      const int jo = o - h * 192;
      const int typ = jo >> 6;  // 0=q 1=k 2=v
      const int ci = jo & 63;
#pragma unroll
      for (int mi = 0; mi < 4; ++mi) {
        const int mrow = m0 + wr * 64 + mi * 16 + l4 * 4;
        const int b = mrow >> 10, t0 = mrow & 1023;
#pragma unroll
        for (int jj = 0; jj < 4; ++jj) {
          const float v = acc[mi][ni][jj] + bo;
          const int t = t0 + jj;
          if (typ == 0)
            Qb[(((size_t)(b * 8 + h) * 1024 + t) << 6) + ci] = f2bf(v * (SCALE_QK * LOG2E));
          else if (typ == 1)
            Kb[(((size_t)(b * 8 + h) * 1024 + t) << 6) + ci] = f2bf(v * SCALE_QK);
          else
            Vb[(((size_t)(b * 8 + h) * 64 + ci) << 10) + t] = f2bf(v);
        }
      }
    } else {
#pragma unroll
      for (int mi = 0; mi < 4; ++mi) {
        const int mrow = m0 + wr * 64 + mi * 16 + l4 * 4;
        const int b = mrow >> 10, t0 = mrow & 1023;
        const size_t base = ((size_t)b * 512 + o) * 1024 + t0;
        const float4 xr = *(const float4*)(xres + base);
        float4 ov;
        ov.x = acc[mi][ni][0] + bo + xr.x;
        ov.y = acc[mi][ni][1] + bo + xr.y;
        ov.z = acc[mi][ni][2] + bo + xr.z;
        ov.w = acc[mi][ni][3] + bo + xr.w;
        *(float4*)(out + base) = ov;
      }
    }
  }
}

// ---------------- flash attention, 32x32 MFMA, swapped QK, in-register P ----------------
// P = exp2(s) (log2e folded into Q), row-sum via MFMA ones-column, normalize at end.
// Per wave: 32 q-rows. Block = 4 waves = 128 q-rows. KVBLK = 64.
__global__ __launch_bounds__(256) void k_attn(const u16* __restrict__ Qb,
                                              const u16* __restrict__ Kb,
                                              const u16* __restrict__ Vb,
                                              u16* __restrict__ ht) {
  __shared__ u16 Ks[2][64][64];   // [s][c], chunk-swizzled
  __shared__ u16 Vs[2][64][64];   // [d][s], chunk-swizzled
  const int tid = threadIdx.x;
  const int lane = tid & 63, wid = tid >> 6;
  const int l31 = lane & 31, hi = lane >> 5;
  const int bh = blockIdx.y, qt = blockIdx.x;
  const int b = bh >> 3, head = bh & 7;
  const int lrow = lane >> 3, lchunk = lane & 7;

  // Q fragments (B-operand of swapped QK): lane(col=t=l31, hi) holds Q[t][c=kc*16+hi*8+e]
  bf16x8 qf[4];
  {
    const u16* qp = Qb + (((size_t)bh * 1024 + qt * 128 + wid * 32 + l31) << 6) + hi * 8;
#pragma unroll
    for (int kc = 0; kc < 4; ++kc) qf[kc] = *(const bf16x8*)(qp + kc * 16);
  }

  // ones B-fragment: B[k][col] = (col==0) -> D col0 = row sums
  bf16x8 onesf;
#pragma unroll
  for (int i = 0; i < 8; ++i) onesf[i] = (l31 == 0) ? (__bf16)1.0f : (__bf16)0.0f;

  f32x16 oacc[2], osum;
#pragma unroll
  for (int r = 0; r < 16; ++r) { oacc[0][r] = 0.f; oacc[1][r] = 0.f; osum[r] = 0.f; }

  auto stageKV = [&](int bi, int st) {
    const int s0 = st * 64;
#pragma unroll
    for (int rd = 0; rd < 2; ++rd) {
      const int rbase = wid * 8 + rd * 32;
      const int r = rbase + lrow;
      const int q = lchunk ^ (r & 7);
      gload16(Kb + (((size_t)bh * 1024 + s0 + r) << 6) + q * 8, &Ks[bi][rbase][0]);
      gload16(Vb + (((size_t)bh * 64 + r) << 10) + s0 + q * 8, &Vs[bi][rbase][0]);
    }
  };

  stageKV(0, 0);
  asm volatile("s_waitcnt vmcnt(0)" ::: "memory");
  __builtin_amdgcn_s_barrier();

  int buf = 0;
  for (int st = 0; st < 16; ++st) {
    if (st < 15) stageKV(buf ^ 1, st + 1);

#pragma unroll
    for (int cb = 0; cb < 2; ++cb) {
      // swapped QK: sacc = K_tile(32s x 64c) * Q^T -> D[s][t]: col=t=l31, row=s(reg,hi)
      f32x16 sacc;
#pragma unroll
      for (int r = 0; r < 16; ++r) sacc[r] = 0.f;
#pragma unroll
      for (int kc = 0; kc < 4; ++kc) {
        const int r = cb * 32 + l31;
        const bf16x8 kb = *(const bf16x8*)&Ks[buf][r][((((kc << 1) | hi)) ^ (r & 7)) << 3];
        sacc = __builtin_amdgcn_mfma_f32_32x32x16_bf16(kb, qf[kc], sacc, 0, 0, 0);
      }
      // p = 2^sacc; s32(reg,hi) = (reg&3) + 4*hi + 8*(reg>>2)
      float p[16];
#pragma unroll
      for (int r = 0; r < 16; ++r)
        asm("v_exp_f32 %0, %1" : "=v"(p[r]) : "v"(sacc[r]));

      // two 16-wide k-steps per cb: build PV A-frag in-register, then MFMA
#pragma unroll
      for (int ksl = 0; ksl < 2; ++ksl) {
        u32 X0, X1, Y0, Y1;
        asm("v_cvt_pk_bf16_f32 %0, %1, %2" : "=v"(X0) : "v"(p[8 * ksl + 0]), "v"(p[8 * ksl + 1]));
        asm("v_cvt_pk_bf16_f32 %0, %1, %2" : "=v"(X1) : "v"(p[8 * ksl + 2]), "v"(p[8 * ksl + 3]));
        asm("v_cvt_pk_bf16_f32 %0, %1, %2" : "=v"(Y0) : "v"(p[8 * ksl + 4]), "v"(p[8 * ksl + 5]));
        asm("v_cvt_pk_bf16_f32 %0, %1, %2" : "=v"(Y1) : "v"(p[8 * ksl + 6]), "v"(p[8 * ksl + 7]));
        // exchange halves: after swap X0=w0(s+0,1), X1=w1(s+2,3), Y0=w2(s+4,5), Y1=w3(s+6,7)
        asm volatile("v_permlane32_swap_b32 %0, %1" : "+v"(X0), "+v"(Y0));
        asm volatile("v_permlane32_swap_b32 %0, %1" : "+v"(X1), "+v"(Y1));
        union { u32 w[4]; bf16x8 v; } pa;
        pa.w[0] = X0; pa.w[1] = X1; pa.w[2] = Y0; pa.w[3] = Y1;
        const int ks = cb * 2 + ksl;  // 16-wide s-step within tile
#pragma unroll
        for (int db = 0; db < 2; ++db) {
          const int r = db * 32 + l31;
          const bf16x8 vb = *(const bf16x8*)&Vs[buf][r][((((ks << 1) | hi)) ^ (r & 7)) << 3];
          oacc[db] = __builtin_amdgcn_mfma_f32_32x32x16_bf16(pa.v, vb, oacc[db], 0, 0, 0);
        }
        osum = __builtin_amdgcn_mfma_f32_32x32x16_bf16(pa.v, onesf, osum, 0, 0, 0);
      }
    }

    asm volatile("s_waitcnt vmcnt(0)" ::: "memory");
    __builtin_amdgcn_s_barrier();
    buf ^= 1;
  }

  // normalize + store: O[t(reg,hi)][d = db*32 + l31]; rowsum at col l31==0 (same hi)
  float inv[16];
#pragma unroll
  for (int r = 0; r < 16; ++r) {
    const float ls = __shfl(osum[r], lane & 32);
    inv[r] = 1.f / ls;
  }
#pragma unroll
  for (int db = 0; db < 2; ++db) {
#pragma unroll
    for (int r = 0; r < 16; ++r) {
      const int t = qt * 128 + wid * 32 + (r & 3) + 8 * (r >> 2) + 4 * hi;
      const int cg = head * 64 + db * 32 + l31;
      ht[((size_t)b * 1024 + t) * 512 + cg] = f2bf(oacc[db][r] * inv[r]);
    }
  }
}

extern "C" void kernel_launch(void* const* d_in, const int* in_sizes, int n_in,
                              void* d_out, int out_size, void* d_ws, size_t ws_size,
                              hipStream_t stream) {
  const float* x = (const float*)d_in[0];
  const float* norm_w = (const float*)d_in[1];
  const float* norm_b = (const float*)d_in[2];
  const float* qkv_w = (const float*)d_in[3];
  const float* qkv_b = (const float*)d_in[4];
  const float* proj_w = (const float*)d_in[5];
  const float* proj_b = (const float*)d_in[6];
  float* out = (float*)d_out;

  char* ws = (char*)d_ws;
  u16* qkvw = (u16*)(ws + 0);          // 1,572,864 B
  u16* projw = (u16*)(ws + 1572864);   //   524,288 B
  u16* gnt = (u16*)(ws + 2097152);     // 16,777,216 B  gn_t[b][t][c]
  u16* Qb = (u16*)(ws + 18874368);     // 16,777,216 B  Q[bh][t][ci]
  u16* Kb = (u16*)(ws + 35651584);     // 16,777,216 B  K[bh][s][ci]
  u16* Vb = (u16*)(ws + 52428800);     // 16,777,216 B  V[bh][ci][s]
  u16* ht = (u16*)(ws + 69206016);     // 16,777,216 B  h_t[b][t][c]

  k_convert<<<768, 256, 0, stream>>>(qkv_w, qkvw, 196608);
  k_convert<<<256, 256, 0, stream>>>(proj_w, projw, 65536);
  k_groupnorm<<<512, 256, 0, stream>>>(x, norm_w, norm_b, gnt);
  k_gemm<0><<<dim3(12, 128), 256, 0, stream>>>(gnt, qkvw, qkv_b, Qb, Kb, Vb, nullptr, nullptr);
  k_attn<<<dim3(8, 128), 256, 0, stream>>>(Qb, Kb, Vb, ht);
  k_gemm<1><<<dim3(4, 128), 256, 0, stream>>>(ht, projw, proj_b, nullptr, nullptr, nullptr, x, out);
}

// Round 4
// 157.040 us; speedup vs baseline: 1.4226x; 1.0974x over previous
//
#include <hip/hip_runtime.h>

typedef unsigned short u16;
typedef unsigned int u32;
typedef __bf16 bf16x8 __attribute__((ext_vector_type(8)));
typedef float f32x4 __attribute__((ext_vector_type(4)));
typedef float f32x16 __attribute__((ext_vector_type(16)));

#define SCALE_QK 0.35355339059327373f  // 64^-0.25
#define LOG2E 1.4426950408889634f

__device__ __forceinline__ u16 f2bf(float f) {
  u32 u = __float_as_uint(f);
  u += 0x7FFFu + ((u >> 16) & 1u);
  return (u16)(u >> 16);
}

__device__ __forceinline__ void gload16(const u16* g, u16* l) {
  __builtin_amdgcn_global_load_lds((const __attribute__((address_space(1))) void*)g,
                                   (__attribute__((address_space(3))) void*)l, 16, 0, 0);
}

// 64-bank-aware row swizzle: folds r bits 0..2 AND 3..4 into the 16B-chunk index
__device__ __forceinline__ int rswz(int r) { return (r & 7) ^ ((r >> 3) & 3); }

// ---------------- weight fp32 -> bf16 ----------------
__global__ __launch_bounds__(256) void k_convert(const float* __restrict__ src,
                                                 u16* __restrict__ dst, int n4) {
  int i = blockIdx.x * 256 + threadIdx.x;
  if (i >= n4) return;
  float4 v = ((const float4*)src)[i];
  u32 lo = (u32)f2bf(v.x) | ((u32)f2bf(v.y) << 16);
  u32 hi = (u32)f2bf(v.z) | ((u32)f2bf(v.w) << 16);
  ((uint2*)dst)[i] = make_uint2(lo, hi);
}

// ---------------- fused GroupNorm: block = (b,g); writes gn_t[b][t][c] bf16 ----------------
__global__ __launch_bounds__(256) void k_groupnorm(const float* __restrict__ x,
                                                   const float* __restrict__ nw,
                                                   const float* __restrict__ nb,
                                                   u16* __restrict__ gnt) {
  const int b = blockIdx.x >> 5;
  const int g = blockIdx.x & 31;
  const int tid = threadIdx.x;
  const float* xg = x + ((size_t)b * 512 + g * 16) * 1024;

  float s = 0.f, ss = 0.f;
#pragma unroll
  for (int it = 0; it < 16; ++it) {
    float4 v = ((const float4*)xg)[tid + it * 256];
    s += v.x + v.y + v.z + v.w;
    ss += v.x * v.x + v.y * v.y + v.z * v.z + v.w * v.w;
  }
#pragma unroll
  for (int off = 32; off >= 1; off >>= 1) {
    s += __shfl_xor(s, off);
    ss += __shfl_xor(ss, off);
  }
  __shared__ float red[8];
  const int wid = tid >> 6, lane = tid & 63;
  if (lane == 0) { red[wid] = s; red[4 + wid] = ss; }
  __syncthreads();
  const float mean = (red[0] + red[1] + red[2] + red[3]) * (1.f / 16384.f);
  const float ex2 = (red[4] + red[5] + red[6] + red[7]) * (1.f / 16384.f);
  const float rstd = rsqrtf(ex2 - mean * mean + 1e-5f);

  const int ci = tid & 15, tt = tid >> 4;
  const int c = g * 16 + ci;
  const float wc = nw[c] * rstd;
  const float bc = nb[c] - mean * wc;
  const float* xc = xg + (size_t)ci * 1024;
  u16* dst = gnt + (size_t)b * 1024 * 512 + c;
#pragma unroll 8
  for (int t = tt; t < 1024; t += 16) {
    dst[(size_t)t * 512] = f2bf(xc[t] * wc + bc);
  }
}

// ---------------- GEMM: D[(b,t)][o] = sum_c A[(b,t)][c] * Bw[o][c]  (K=512) ----------------
// 2-phase double-buffered staging (T3 minimum); flat grid, m-major for XCD L2 reuse.
template <int MODE>
__global__ __launch_bounds__(256) void k_gemm(const u16* __restrict__ A,
                                              const u16* __restrict__ Bw,
                                              const float* __restrict__ bias,
                                              u16* __restrict__ Qb, u16* __restrict__ Kb,
                                              u16* __restrict__ Vb,
                                              const float* __restrict__ xres,
                                              float* __restrict__ out) {
  __shared__ u16 As[2][128][64];
  __shared__ u16 Bs[2][128][64];
  const int tid = threadIdx.x;
  const int lane = tid & 63, wid = tid >> 6;
  const int wr = wid >> 1, wc = wid & 1;
  const int fid = blockIdx.x;
  const int m0 = (fid & 127) * 128;   // fid%8 == m%8 -> same-A-panel blocks share an XCD
  const int n0 = (fid >> 7) * 128;
  const int l15 = lane & 15, l4 = lane >> 4;
  const f32x4 fzero = {0.f, 0.f, 0.f, 0.f};

  f32x4 acc[4][4];
#pragma unroll
  for (int i = 0; i < 4; ++i)
#pragma unroll
    for (int j = 0; j < 4; ++j) acc[i][j] = fzero;

  const int lrow = lane >> 3;
  const int lchunk = lane & 7;

  auto stage = [&](int bi, int kt) {
#pragma unroll
    for (int rd = 0; rd < 4; ++rd) {
      const int rbase = wid * 8 + rd * 32;
      const int r = rbase + lrow;
      const int q = lchunk ^ (r & 7);
      gload16(A + ((size_t)(m0 + r) * 512 + kt * 64 + q * 8), &As[bi][rbase][0]);
      gload16(Bw + ((size_t)(n0 + r) * 512 + kt * 64 + q * 8), &Bs[bi][rbase][0]);
    }
  };

  stage(0, 0);
  asm volatile("s_waitcnt vmcnt(0)" ::: "memory");
  __builtin_amdgcn_s_barrier();

  int buf = 0;
  for (int kt = 0; kt < 8; ++kt) {
    if (kt < 7) stage(buf ^ 1, kt + 1);
#pragma unroll
    for (int ks = 0; ks < 2; ++ks) {
      bf16x8 af[4], bfr[4];
#pragma unroll
      for (int mi = 0; mi < 4; ++mi) {
        const int row = wr * 64 + mi * 16 + l15;
        af[mi] = *(const bf16x8*)&As[buf][row][(((ks << 2) + l4) ^ (row & 7)) << 3];
      }
#pragma unroll
      for (int ni = 0; ni < 4; ++ni) {
        const int row = wc * 64 + ni * 16 + l15;
        bfr[ni] = *(const bf16x8*)&Bs[buf][row][(((ks << 2) + l4) ^ (row & 7)) << 3];
      }
#pragma unroll
      for (int mi = 0; mi < 4; ++mi)
#pragma unroll
        for (int ni = 0; ni < 4; ++ni)
          acc[mi][ni] = __builtin_amdgcn_mfma_f32_16x16x32_bf16(af[mi], bfr[ni], acc[mi][ni], 0, 0, 0);
    }
    asm volatile("s_waitcnt lgkmcnt(0)" ::: "memory");
    asm volatile("s_waitcnt vmcnt(0)" ::: "memory");
    __builtin_amdgcn_s_barrier();
    buf ^= 1;
  }

#pragma unroll
  for (int ni = 0; ni < 4; ++ni) {
    const int o = n0 + wc * 64 + ni * 16 + l15;
    const float bo = bias[o];
    if (MODE == 0) {
      const int h = o / 192;
      const int jo = o - h * 192;
      const int typ = jo >> 6;  // 0=q 1=k 2=v
      const int ci = jo & 63;
#pragma unroll
      for (int mi = 0; mi < 4; ++mi) {
        const int mrow = m0 + wr * 64 + mi * 16 + l4 * 4;
        const int b = mrow >> 10, t0 = mrow & 1023;
#pragma unroll
        for (int jj = 0; jj < 4; ++jj) {
          const float v = acc[mi][ni][jj] + bo;
          const int t = t0 + jj;
          if (typ == 0)
            Qb[(((size_t)(b * 8 + h) * 1024 + t) << 6) + ci] = f2bf(v * (SCALE_QK * LOG2E));
          else if (typ == 1)
            Kb[(((size_t)(b * 8 + h) * 1024 + t) << 6) + ci] = f2bf(v * SCALE_QK);
          else
            Vb[(((size_t)(b * 8 + h) * 64 + ci) << 10) + t] = f2bf(v);
        }
      }
    } else {
#pragma unroll
      for (int mi = 0; mi < 4; ++mi) {
        const int mrow = m0 + wr * 64 + mi * 16 + l4 * 4;
        const int b = mrow >> 10, t0 = mrow & 1023;
        const size_t base = ((size_t)b * 512 + o) * 1024 + t0;
        const float4 xr = *(const float4*)(xres + base);
        float4 ov;
        ov.x = acc[mi][ni][0] + bo + xr.x;
        ov.y = acc[mi][ni][1] + bo + xr.y;
        ov.z = acc[mi][ni][2] + bo + xr.z;
        ov.w = acc[mi][ni][3] + bo + xr.w;
        *(float4*)(out + base) = ov;
      }
    }
  }
}

// ---------------- flash attention, 32x32 MFMA, swapped QK, in-register P ----------------
// P = exp2(s) (log2e folded into Q), row-sum via MFMA ones-column, normalize at end.
// Per wave: 32 q-rows. Block = 4 waves = 128 q-rows. KVBLK = 64.
// Flat grid, qt-major: fid%8 == bh%8 -> one bh's K/V stays in one XCD's L2.
__global__ __launch_bounds__(256) void k_attn(const u16* __restrict__ Qb,
                                              const u16* __restrict__ Kb,
                                              const u16* __restrict__ Vb,
                                              u16* __restrict__ ht) {
  __shared__ u16 Ks[2][64][64];   // [s][c], rswz chunk-swizzled
  __shared__ u16 Vs[2][64][64];   // [d][s], rswz chunk-swizzled
  const int tid = threadIdx.x;
  const int lane = tid & 63, wid = tid >> 6;
  const int l31 = lane & 31, hi = lane >> 5;
  const int fid = blockIdx.x;
  const int bh = fid & 127, qt = fid >> 7;
  const int b = bh >> 3, head = bh & 7;
  const int lrow = lane >> 3, lchunk = lane & 7;
  const int rsw = rswz(l31);  // row-swizzle for reads (r = cb*32 + l31; bits 3..4 of cb*32 vanish mod 4)

  // Q fragments (B-operand of swapped QK): lane(col=t=l31, hi) holds Q[t][c=kc*16+hi*8+e]
  bf16x8 qf[4];
  {
    const u16* qp = Qb + (((size_t)bh * 1024 + qt * 128 + wid * 32 + l31) << 6) + hi * 8;
#pragma unroll
    for (int kc = 0; kc < 4; ++kc) qf[kc] = *(const bf16x8*)(qp + kc * 16);
  }

  // ones B-fragment: B[k][col] = (col==0) -> D col0 = row sums
  bf16x8 onesf;
#pragma unroll
  for (int i = 0; i < 8; ++i) onesf[i] = (l31 == 0) ? (__bf16)1.0f : (__bf16)0.0f;

  f32x16 oacc[2], osum;
#pragma unroll
  for (int r = 0; r < 16; ++r) { oacc[0][r] = 0.f; oacc[1][r] = 0.f; osum[r] = 0.f; }

  auto stageKV = [&](int bi, int st) {
    const int s0 = st * 64;
#pragma unroll
    for (int rd = 0; rd < 2; ++rd) {
      const int rbase = wid * 8 + rd * 32;
      const int r = rbase + lrow;
      const int q = lchunk ^ rswz(r);
      gload16(Kb + (((size_t)bh * 1024 + s0 + r) << 6) + q * 8, &Ks[bi][rbase][0]);
      gload16(Vb + (((size_t)bh * 64 + r) << 10) + s0 + q * 8, &Vs[bi][rbase][0]);
    }
  };

  stageKV(0, 0);
  asm volatile("s_waitcnt vmcnt(0)" ::: "memory");
  __builtin_amdgcn_s_barrier();

  int buf = 0;
  for (int st = 0; st < 16; ++st) {
    if (st < 15) stageKV(buf ^ 1, st + 1);

#pragma unroll
    for (int cb = 0; cb < 2; ++cb) {
      // swapped QK: sacc = K_tile(32s x 64c) * Q^T -> D[s][t]: col=t=l31, row=s(reg,hi)
      f32x16 sacc;
#pragma unroll
      for (int r = 0; r < 16; ++r) sacc[r] = 0.f;
      __builtin_amdgcn_s_setprio(1);
#pragma unroll
      for (int kc = 0; kc < 4; ++kc) {
        const int r = cb * 32 + l31;
        const bf16x8 kb = *(const bf16x8*)&Ks[buf][r][((((kc << 1) | hi)) ^ rsw) << 3];
        sacc = __builtin_amdgcn_mfma_f32_32x32x16_bf16(kb, qf[kc], sacc, 0, 0, 0);
      }
      __builtin_amdgcn_s_setprio(0);
      // p = 2^sacc; s32(reg,hi) = (reg&3) + 4*hi + 8*(reg>>2)
      float p[16];
#pragma unroll
      for (int r = 0; r < 16; ++r)
        asm("v_exp_f32 %0, %1" : "=v"(p[r]) : "v"(sacc[r]));

      // two 16-wide k-steps per cb: build PV A-frag in-register, then MFMA
#pragma unroll
      for (int ksl = 0; ksl < 2; ++ksl) {
        u32 X0, X1, Y0, Y1;
        asm("v_cvt_pk_bf16_f32 %0, %1, %2" : "=v"(X0) : "v"(p[8 * ksl + 0]), "v"(p[8 * ksl + 1]));
        asm("v_cvt_pk_bf16_f32 %0, %1, %2" : "=v"(X1) : "v"(p[8 * ksl + 2]), "v"(p[8 * ksl + 3]));
        asm("v_cvt_pk_bf16_f32 %0, %1, %2" : "=v"(Y0) : "v"(p[8 * ksl + 4]), "v"(p[8 * ksl + 5]));
        asm("v_cvt_pk_bf16_f32 %0, %1, %2" : "=v"(Y1) : "v"(p[8 * ksl + 6]), "v"(p[8 * ksl + 7]));
        // exchange halves: after swap X0=w0(s+0,1), X1=w1(s+2,3), Y0=w2(s+4,5), Y1=w3(s+6,7)
        asm volatile("v_permlane32_swap_b32 %0, %1" : "+v"(X0), "+v"(Y0));
        asm volatile("v_permlane32_swap_b32 %0, %1" : "+v"(X1), "+v"(Y1));
        union { u32 w[4]; bf16x8 v; } pa;
        pa.w[0] = X0; pa.w[1] = X1; pa.w[2] = Y0; pa.w[3] = Y1;
        const int ks = cb * 2 + ksl;  // 16-wide s-step within tile
        __builtin_amdgcn_s_setprio(1);
#pragma unroll
        for (int db = 0; db < 2; ++db) {
          const int r = db * 32 + l31;
          const bf16x8 vb = *(const bf16x8*)&Vs[buf][r][((((ks << 1) | hi)) ^ rsw) << 3];
          oacc[db] = __builtin_amdgcn_mfma_f32_32x32x16_bf16(pa.v, vb, oacc[db], 0, 0, 0);
        }
        osum = __builtin_amdgcn_mfma_f32_32x32x16_bf16(pa.v, onesf, osum, 0, 0, 0);
        __builtin_amdgcn_s_setprio(0);
      }
    }

    asm volatile("s_waitcnt lgkmcnt(0)" ::: "memory");
    asm volatile("s_waitcnt vmcnt(0)" ::: "memory");
    __builtin_amdgcn_s_barrier();
    buf ^= 1;
  }

  // normalize + store: O[t(reg,hi)][d = db*32 + l31]; rowsum at col l31==0 (same hi)
  float inv[16];
#pragma unroll
  for (int r = 0; r < 16; ++r) {
    const float ls = __shfl(osum[r], lane & 32);
    inv[r] = 1.f / ls;
  }
#pragma unroll
  for (int db = 0; db < 2; ++db) {
#pragma unroll
    for (int r = 0; r < 16; ++r) {
      const int t = qt * 128 + wid * 32 + (r & 3) + 8 * (r >> 2) + 4 * hi;
      const int cg = head * 64 + db * 32 + l31;
      ht[((size_t)b * 1024 + t) * 512 + cg] = f2bf(oacc[db][r] * inv[r]);
    }
  }
}

extern "C" void kernel_launch(void* const* d_in, const int* in_sizes, int n_in,
                              void* d_out, int out_size, void* d_ws, size_t ws_size,
                              hipStream_t stream) {
  const float* x = (const float*)d_in[0];
  const float* norm_w = (const float*)d_in[1];
  const float* norm_b = (const float*)d_in[2];
  const float* qkv_w = (const float*)d_in[3];
  const float* qkv_b = (const float*)d_in[4];
  const float* proj_w = (const float*)d_in[5];
  const float* proj_b = (const float*)d_in[6];
  float* out = (float*)d_out;

  char* ws = (char*)d_ws;
  u16* qkvw = (u16*)(ws + 0);          // 1,572,864 B
  u16* projw = (u16*)(ws + 1572864);   //   524,288 B
  u16* gnt = (u16*)(ws + 2097152);     // 16,777,216 B  gn_t[b][t][c]
  u16* Qb = (u16*)(ws + 18874368);     // 16,777,216 B  Q[bh][t][ci]
  u16* Kb = (u16*)(ws + 35651584);     // 16,777,216 B  K[bh][s][ci]
  u16* Vb = (u16*)(ws + 52428800);     // 16,777,216 B  V[bh][ci][s]
  u16* ht = (u16*)(ws + 69206016);     // 16,777,216 B  h_t[b][t][c]

  k_convert<<<768, 256, 0, stream>>>(qkv_w, qkvw, 196608);
  k_convert<<<256, 256, 0, stream>>>(proj_w, projw, 65536);
  k_groupnorm<<<512, 256, 0, stream>>>(x, norm_w, norm_b, gnt);
  k_gemm<0><<<1536, 256, 0, stream>>>(gnt, qkvw, qkv_b, Qb, Kb, Vb, nullptr, nullptr);
  k_attn<<<1024, 256, 0, stream>>>(Qb, Kb, Vb, ht);
  k_gemm<1><<<512, 256, 0, stream>>>(ht, projw, proj_b, nullptr, nullptr, nullptr, x, out);
}

// Round 7
// 155.695 us; speedup vs baseline: 1.4349x; 1.0086x over previous
//
#include <hip/hip_runtime.h>

typedef unsigned short u16;
typedef unsigned int u32;
typedef __bf16 bf16x8 __attribute__((ext_vector_type(8)));
typedef float f32x4 __attribute__((ext_vector_type(4)));
typedef float f32x16 __attribute__((ext_vector_type(16)));

#define SCALE_QK 0.35355339059327373f  // 64^-0.25
#define LOG2E 1.4426950408889634f

__device__ __forceinline__ u16 f2bf(float f) {
  u32 u = __float_as_uint(f);
  u += 0x7FFFu + ((u >> 16) & 1u);
  return (u16)(u >> 16);
}

__device__ __forceinline__ void gload16(const u16* g, u16* l) {
  __builtin_amdgcn_global_load_lds((const __attribute__((address_space(1))) void*)g,
                                   (__attribute__((address_space(3))) void*)l, 16, 0, 0);
}

// row swizzle used by the (known-good) round-4 attention layout
__device__ __forceinline__ int rswz(int r) { return (r & 7) ^ ((r >> 3) & 3); }

// ---------------- weight fp32 -> bf16 ----------------
__global__ __launch_bounds__(256) void k_convert(const float* __restrict__ src,
                                                 u16* __restrict__ dst, int n4) {
  int i = blockIdx.x * 256 + threadIdx.x;
  if (i >= n4) return;
  float4 v = ((const float4*)src)[i];
  u32 lo = (u32)f2bf(v.x) | ((u32)f2bf(v.y) << 16);
  u32 hi = (u32)f2bf(v.z) | ((u32)f2bf(v.w) << 16);
  ((uint2*)dst)[i] = make_uint2(lo, hi);
}

// ---------------- fused GroupNorm: block = (b,g); writes gn_t[b][t][c] bf16 ----------------
__global__ __launch_bounds__(256) void k_groupnorm(const float* __restrict__ x,
                                                   const float* __restrict__ nw,
                                                   const float* __restrict__ nb,
                                                   u16* __restrict__ gnt) {
  const int b = blockIdx.x >> 5;
  const int g = blockIdx.x & 31;
  const int tid = threadIdx.x;
  const float* xg = x + ((size_t)b * 512 + g * 16) * 1024;

  float s = 0.f, ss = 0.f;
#pragma unroll
  for (int it = 0; it < 16; ++it) {
    float4 v = ((const float4*)xg)[tid + it * 256];
    s += v.x + v.y + v.z + v.w;
    ss += v.x * v.x + v.y * v.y + v.z * v.z + v.w * v.w;
  }
#pragma unroll
  for (int off = 32; off >= 1; off >>= 1) {
    s += __shfl_xor(s, off);
    ss += __shfl_xor(ss, off);
  }
  __shared__ float red[8];
  const int wid = tid >> 6, lane = tid & 63;
  if (lane == 0) { red[wid] = s; red[4 + wid] = ss; }
  __syncthreads();
  const float mean = (red[0] + red[1] + red[2] + red[3]) * (1.f / 16384.f);
  const float ex2 = (red[4] + red[5] + red[6] + red[7]) * (1.f / 16384.f);
  const float rstd = rsqrtf(ex2 - mean * mean + 1e-5f);

  const int ci = tid & 15, tt = tid >> 4;
  const int c = g * 16 + ci;
  const float wc = nw[c] * rstd;
  const float bc = nb[c] - mean * wc;
  const float* xc = xg + (size_t)ci * 1024;
  u16* dst = gnt + (size_t)b * 1024 * 512 + c;
#pragma unroll 8
  for (int t = tt; t < 1024; t += 16) {
    dst[(size_t)t * 512] = f2bf(xc[t] * wc + bc);
  }
}

// ---------------- GEMM: D[(b,t)][o] = sum_c A[(b,t)][c] * Bw[o][c]  (K=512) ----------------
// 512 threads / 8 waves, 128x128 tile, wave = 32x64. Double-buffered 2-phase.
// Flat grid, m-major: fid%8 == m-tile%8 -> same-A-panel blocks share an XCD L2.
template <int MODE>
__global__ __launch_bounds__(512) void k_gemm(const u16* __restrict__ A,
                                              const u16* __restrict__ Bw,
                                              const float* __restrict__ bias,
                                              u16* __restrict__ Qb, u16* __restrict__ Kb,
                                              u16* __restrict__ Vb,
                                              const float* __restrict__ xres,
                                              float* __restrict__ out) {
  __shared__ u16 As[2][128][64];
  __shared__ u16 Bs[2][128][64];
  const int tid = threadIdx.x;
  const int lane = tid & 63, wid = tid >> 6;
  const int wr = wid >> 1, wc = wid & 1;     // wave tile: rows wr*32, cols wc*64
  const int fid = blockIdx.x;
  const int m0 = (fid & 127) * 128;
  const int n0 = (fid >> 7) * 128;
  const int l15 = lane & 15, l4 = lane >> 4;
  const f32x4 fzero = {0.f, 0.f, 0.f, 0.f};

  f32x4 acc[2][4];
#pragma unroll
  for (int i = 0; i < 2; ++i)
#pragma unroll
    for (int j = 0; j < 4; ++j) acc[i][j] = fzero;

  const int lrow = (tid & 63) >> 3;
  const int lchunk = tid & 7;

  auto stage = [&](int bi, int kt) {
#pragma unroll
    for (int rd = 0; rd < 2; ++rd) {
      const int rbase = wid * 8 + rd * 64;
      const int r = rbase + lrow;
      const int q = lchunk ^ (r & 7);
      gload16(A + ((size_t)(m0 + r) * 512 + kt * 64 + q * 8), &As[bi][rbase][0]);
      gload16(Bw + ((size_t)(n0 + r) * 512 + kt * 64 + q * 8), &Bs[bi][rbase][0]);
    }
  };

  stage(0, 0);
  asm volatile("s_waitcnt vmcnt(0)" ::: "memory");
  __builtin_amdgcn_s_barrier();

  int buf = 0;
  for (int kt = 0; kt < 8; ++kt) {
    if (kt < 7) stage(buf ^ 1, kt + 1);
#pragma unroll
    for (int ks = 0; ks < 2; ++ks) {
      bf16x8 af[2], bfr[4];
#pragma unroll
      for (int mi = 0; mi < 2; ++mi) {
        const int row = wr * 32 + mi * 16 + l15;
        af[mi] = *(const bf16x8*)&As[buf][row][(((ks << 2) + l4) ^ (row & 7)) << 3];
      }
#pragma unroll
      for (int ni = 0; ni < 4; ++ni) {
        const int row = wc * 64 + ni * 16 + l15;
        bfr[ni] = *(const bf16x8*)&Bs[buf][row][(((ks << 2) + l4) ^ (row & 7)) << 3];
      }
#pragma unroll
      for (int mi = 0; mi < 2; ++mi)
#pragma unroll
        for (int ni = 0; ni < 4; ++ni)
          acc[mi][ni] = __builtin_amdgcn_mfma_f32_16x16x32_bf16(af[mi], bfr[ni], acc[mi][ni], 0, 0, 0);
    }
    asm volatile("s_waitcnt lgkmcnt(0)" ::: "memory");
    asm volatile("s_waitcnt vmcnt(0)" ::: "memory");
    __builtin_amdgcn_s_barrier();
    buf ^= 1;
  }

#pragma unroll
  for (int ni = 0; ni < 4; ++ni) {
    const int o = n0 + wc * 64 + ni * 16 + l15;
    const float bo = bias[o];
    if (MODE == 0) {
      const int h = o / 192;
      const int jo = o - h * 192;
      const int typ = jo >> 6;  // 0=q 1=k 2=v
      const int ci = jo & 63;
#pragma unroll
      for (int mi = 0; mi < 2; ++mi) {
        const int mrow = m0 + wr * 32 + mi * 16 + l4 * 4;
        const int b = mrow >> 10, t0 = mrow & 1023;
#pragma unroll
        for (int jj = 0; jj < 4; ++jj) {
          const float v = acc[mi][ni][jj] + bo;
          const int t = t0 + jj;
          if (typ == 0)
            Qb[(((size_t)(b * 8 + h) * 1024 + t) << 6) + ci] = f2bf(v * (SCALE_QK * LOG2E));
          else if (typ == 1)
            Kb[(((size_t)(b * 8 + h) * 1024 + t) << 6) + ci] = f2bf(v * SCALE_QK);
          else
            Vb[(((size_t)(b * 8 + h) * 64 + ci) << 10) + t] = f2bf(v);
        }
      }
    } else {
#pragma unroll
      for (int mi = 0; mi < 2; ++mi) {
        const int mrow = m0 + wr * 32 + mi * 16 + l4 * 4;
        const int b = mrow >> 10, t0 = mrow & 1023;
        const size_t base = ((size_t)b * 512 + o) * 1024 + t0;
        const float4 xr = *(const float4*)(xres + base);
        float4 ov;
        ov.x = acc[mi][ni][0] + bo + xr.x;
        ov.y = acc[mi][ni][1] + bo + xr.y;
        ov.z = acc[mi][ni][2] + bo + xr.z;
        ov.w = acc[mi][ni][3] + bo + xr.w;
        *(float4*)(out + base) = ov;
      }
    }
  }
}

// ---------------- flash attention (round-4 known-good version, verbatim) ----------------
// 32x32 MFMA, swapped QK, in-register P. 256 threads / 4 waves, 128 q-rows/block.
__global__ __launch_bounds__(256) void k_attn(const u16* __restrict__ Qb,
                                              const u16* __restrict__ Kb,
                                              const u16* __restrict__ Vb,
                                              u16* __restrict__ ht) {
  __shared__ u16 Ks[2][64][64];   // [s][c], rswz chunk-swizzled
  __shared__ u16 Vs[2][64][64];   // [d][s], rswz chunk-swizzled
  const int tid = threadIdx.x;
  const int lane = tid & 63, wid = tid >> 6;
  const int l31 = lane & 31, hi = lane >> 5;
  const int fid = blockIdx.x;
  const int bh = fid & 127, qt = fid >> 7;
  const int b = bh >> 3, head = bh & 7;
  const int lrow = lane >> 3, lchunk = lane & 7;
  const int rsw = rswz(l31);

  bf16x8 qf[4];
  {
    const u16* qp = Qb + (((size_t)bh * 1024 + qt * 128 + wid * 32 + l31) << 6) + hi * 8;
#pragma unroll
    for (int kc = 0; kc < 4; ++kc) qf[kc] = *(const bf16x8*)(qp + kc * 16);
  }

  bf16x8 onesf;
#pragma unroll
  for (int i = 0; i < 8; ++i) onesf[i] = (l31 == 0) ? (__bf16)1.0f : (__bf16)0.0f;

  f32x16 oacc[2], osum;
#pragma unroll
  for (int r = 0; r < 16; ++r) { oacc[0][r] = 0.f; oacc[1][r] = 0.f; osum[r] = 0.f; }

  auto stageKV = [&](int bi, int st) {
    const int s0 = st * 64;
#pragma unroll
    for (int rd = 0; rd < 2; ++rd) {
      const int rbase = wid * 8 + rd * 32;
      const int r = rbase + lrow;
      const int q = lchunk ^ rswz(r);
      gload16(Kb + (((size_t)bh * 1024 + s0 + r) << 6) + q * 8, &Ks[bi][rbase][0]);
      gload16(Vb + (((size_t)bh * 64 + r) << 10) + s0 + q * 8, &Vs[bi][rbase][0]);
    }
  };

  stageKV(0, 0);
  asm volatile("s_waitcnt vmcnt(0)" ::: "memory");
  __builtin_amdgcn_s_barrier();

  int buf = 0;
  for (int st = 0; st < 16; ++st) {
    if (st < 15) stageKV(buf ^ 1, st + 1);

#pragma unroll
    for (int cb = 0; cb < 2; ++cb) {
      f32x16 sacc;
#pragma unroll
      for (int r = 0; r < 16; ++r) sacc[r] = 0.f;
      __builtin_amdgcn_s_setprio(1);
#pragma unroll
      for (int kc = 0; kc < 4; ++kc) {
        const int r = cb * 32 + l31;
        const bf16x8 kb = *(const bf16x8*)&Ks[buf][r][((((kc << 1) | hi)) ^ rsw) << 3];
        sacc = __builtin_amdgcn_mfma_f32_32x32x16_bf16(kb, qf[kc], sacc, 0, 0, 0);
      }
      __builtin_amdgcn_s_setprio(0);
      float p[16];
#pragma unroll
      for (int r = 0; r < 16; ++r)
        asm("v_exp_f32 %0, %1" : "=v"(p[r]) : "v"(sacc[r]));

#pragma unroll
      for (int ksl = 0; ksl < 2; ++ksl) {
        u32 X0, X1, Y0, Y1;
        asm("v_cvt_pk_bf16_f32 %0, %1, %2" : "=v"(X0) : "v"(p[8 * ksl + 0]), "v"(p[8 * ksl + 1]));
        asm("v_cvt_pk_bf16_f32 %0, %1, %2" : "=v"(X1) : "v"(p[8 * ksl + 2]), "v"(p[8 * ksl + 3]));
        asm("v_cvt_pk_bf16_f32 %0, %1, %2" : "=v"(Y0) : "v"(p[8 * ksl + 4]), "v"(p[8 * ksl + 5]));
        asm("v_cvt_pk_bf16_f32 %0, %1, %2" : "=v"(Y1) : "v"(p[8 * ksl + 6]), "v"(p[8 * ksl + 7]));
        asm volatile("v_permlane32_swap_b32 %0, %1" : "+v"(X0), "+v"(Y0));
        asm volatile("v_permlane32_swap_b32 %0, %1" : "+v"(X1), "+v"(Y1));
        union { u32 w[4]; bf16x8 v; } pa;
        pa.w[0] = X0; pa.w[1] = X1; pa.w[2] = Y0; pa.w[3] = Y1;
        const int ks = cb * 2 + ksl;
        __builtin_amdgcn_s_setprio(1);
#pragma unroll
        for (int db = 0; db < 2; ++db) {
          const int r = db * 32 + l31;
          const bf16x8 vb = *(const bf16x8*)&Vs[buf][r][((((ks << 1) | hi)) ^ rsw) << 3];
          oacc[db] = __builtin_amdgcn_mfma_f32_32x32x16_bf16(pa.v, vb, oacc[db], 0, 0, 0);
        }
        osum = __builtin_amdgcn_mfma_f32_32x32x16_bf16(pa.v, onesf, osum, 0, 0, 0);
        __builtin_amdgcn_s_setprio(0);
      }
    }

    asm volatile("s_waitcnt lgkmcnt(0)" ::: "memory");
    asm volatile("s_waitcnt vmcnt(0)" ::: "memory");
    __builtin_amdgcn_s_barrier();
    buf ^= 1;
  }

  float inv[16];
#pragma unroll
  for (int r = 0; r < 16; ++r) {
    const float ls = __shfl(osum[r], lane & 32);
    inv[r] = 1.f / ls;
  }
#pragma unroll
  for (int db = 0; db < 2; ++db) {
#pragma unroll
    for (int r = 0; r < 16; ++r) {
      const int t = qt * 128 + wid * 32 + (r & 3) + 8 * (r >> 2) + 4 * hi;
      const int cg = head * 64 + db * 32 + l31;
      ht[((size_t)b * 1024 + t) * 512 + cg] = f2bf(oacc[db][r] * inv[r]);
    }
  }
}

extern "C" void kernel_launch(void* const* d_in, const int* in_sizes, int n_in,
                              void* d_out, int out_size, void* d_ws, size_t ws_size,
                              hipStream_t stream) {
  const float* x = (const float*)d_in[0];
  const float* norm_w = (const float*)d_in[1];
  const float* norm_b = (const float*)d_in[2];
  const float* qkv_w = (const float*)d_in[3];
  const float* qkv_b = (const float*)d_in[4];
  const float* proj_w = (const float*)d_in[5];
  const float* proj_b = (const float*)d_in[6];
  float* out = (float*)d_out;

  char* ws = (char*)d_ws;
  u16* qkvw = (u16*)(ws + 0);          // 1,572,864 B
  u16* projw = (u16*)(ws + 1572864);   //   524,288 B
  u16* gnt = (u16*)(ws + 2097152);     // 16,777,216 B  gn_t[b][t][c]
  u16* Qb = (u16*)(ws + 18874368);     // 16,777,216 B  Q[bh][t][ci]
  u16* Kb = (u16*)(ws + 35651584);     // 16,777,216 B  K[bh][s][ci]
  u16* Vb = (u16*)(ws + 52428800);     // 16,777,216 B  V[bh][ci][s]
  u16* ht = (u16*)(ws + 69206016);     // 16,777,216 B  h_t[b][t][c]

  k_convert<<<768, 256, 0, stream>>>(qkv_w, qkvw, 196608);
  k_convert<<<256, 256, 0, stream>>>(proj_w, projw, 65536);
  k_groupnorm<<<512, 256, 0, stream>>>(x, norm_w, norm_b, gnt);
  k_gemm<0><<<1536, 512, 0, stream>>>(gnt, qkvw, qkv_b, Qb, Kb, Vb, nullptr, nullptr);
  k_attn<<<1024, 256, 0, stream>>>(Qb, Kb, Vb, ht);
  k_gemm<1><<<512, 512, 0, stream>>>(ht, projw, proj_b, nullptr, nullptr, nullptr, x, out);
}

// Round 8
// 153.386 us; speedup vs baseline: 1.4565x; 1.0151x over previous
//
#include <hip/hip_runtime.h>

typedef unsigned short u16;
typedef unsigned int u32;
typedef __bf16 bf16x8 __attribute__((ext_vector_type(8)));
typedef float f32x4 __attribute__((ext_vector_type(4)));
typedef float f32x16 __attribute__((ext_vector_type(16)));

#define SCALE_QK 0.35355339059327373f  // 64^-0.25
#define LOG2E 1.4426950408889634f

__device__ __forceinline__ u16 f2bf(float f) {
  u32 u = __float_as_uint(f);
  u += 0x7FFFu + ((u >> 16) & 1u);
  return (u16)(u >> 16);
}

__device__ __forceinline__ void gload16(const u16* g, u16* l) {
  __builtin_amdgcn_global_load_lds((const __attribute__((address_space(1))) void*)g,
                                   (__attribute__((address_space(3))) void*)l, 16, 0, 0);
}

// row swizzle for the attention K/V LDS layout (conflict-free, measured r7: 0 conflicts)
__device__ __forceinline__ int rswz(int r) { return (r & 7) ^ ((r >> 3) & 3); }

// ---------------- weight fp32 -> bf16 ----------------
__global__ __launch_bounds__(256) void k_convert(const float* __restrict__ src,
                                                 u16* __restrict__ dst, int n4) {
  int i = blockIdx.x * 256 + threadIdx.x;
  if (i >= n4) return;
  float4 v = ((const float4*)src)[i];
  u32 lo = (u32)f2bf(v.x) | ((u32)f2bf(v.y) << 16);
  u32 hi = (u32)f2bf(v.z) | ((u32)f2bf(v.w) << 16);
  ((uint2*)dst)[i] = make_uint2(lo, hi);
}

// ---------------- fused GroupNorm: block = (b,g); writes gn_t[b][t][c] bf16 ----------------
__global__ __launch_bounds__(256) void k_groupnorm(const float* __restrict__ x,
                                                   const float* __restrict__ nw,
                                                   const float* __restrict__ nb,
                                                   u16* __restrict__ gnt) {
  const int b = blockIdx.x >> 5;
  const int g = blockIdx.x & 31;
  const int tid = threadIdx.x;
  const float* xg = x + ((size_t)b * 512 + g * 16) * 1024;

  float s = 0.f, ss = 0.f;
#pragma unroll
  for (int it = 0; it < 16; ++it) {
    float4 v = ((const float4*)xg)[tid + it * 256];
    s += v.x + v.y + v.z + v.w;
    ss += v.x * v.x + v.y * v.y + v.z * v.z + v.w * v.w;
  }
#pragma unroll
  for (int off = 32; off >= 1; off >>= 1) {
    s += __shfl_xor(s, off);
    ss += __shfl_xor(ss, off);
  }
  __shared__ float red[8];
  const int wid = tid >> 6, lane = tid & 63;
  if (lane == 0) { red[wid] = s; red[4 + wid] = ss; }
  __syncthreads();
  const float mean = (red[0] + red[1] + red[2] + red[3]) * (1.f / 16384.f);
  const float ex2 = (red[4] + red[5] + red[6] + red[7]) * (1.f / 16384.f);
  const float rstd = rsqrtf(ex2 - mean * mean + 1e-5f);

  const int ci = tid & 15, tt = tid >> 4;
  const int c = g * 16 + ci;
  const float wc = nw[c] * rstd;
  const float bc = nb[c] - mean * wc;
  const float* xc = xg + (size_t)ci * 1024;
  u16* dst = gnt + (size_t)b * 1024 * 512 + c;
#pragma unroll 8
  for (int t = tt; t < 1024; t += 16) {
    dst[(size_t)t * 512] = f2bf(xc[t] * wc + bc);
  }
}

// ---------------- GEMM: D[(b,t)][o] = sum_c A[(b,t)][c] * Bw[o][c]  (K=512) ----------------
// 512 threads / 8 waves, 128x128 tile. Double-buffered, ROTATED loop:
// waits+barrier at TOP of iter -> stage(i)'s loads drain a full compute phase after issue.
template <int MODE>
__global__ __launch_bounds__(512) void k_gemm(const u16* __restrict__ A,
                                              const u16* __restrict__ Bw,
                                              const float* __restrict__ bias,
                                              u16* __restrict__ Qb, u16* __restrict__ Kb,
                                              u16* __restrict__ Vb,
                                              const float* __restrict__ xres,
                                              float* __restrict__ out) {
  __shared__ u16 As[2][128][64];
  __shared__ u16 Bs[2][128][64];
  const int tid = threadIdx.x;
  const int lane = tid & 63, wid = tid >> 6;
  const int wr = wid >> 1, wc = wid & 1;     // wave tile: rows wr*32, cols wc*64
  const int fid = blockIdx.x;
  const int m0 = (fid & 127) * 128;
  const int n0 = (fid >> 7) * 128;
  const int l15 = lane & 15, l4 = lane >> 4;
  const f32x4 fzero = {0.f, 0.f, 0.f, 0.f};

  f32x4 acc[2][4];
#pragma unroll
  for (int i = 0; i < 2; ++i)
#pragma unroll
    for (int j = 0; j < 4; ++j) acc[i][j] = fzero;

  const int lrow = (tid & 63) >> 3;
  const int lchunk = tid & 7;

  auto stage = [&](int bi, int kt) {
#pragma unroll
    for (int rd = 0; rd < 2; ++rd) {
      const int rbase = wid * 8 + rd * 64;
      const int r = rbase + lrow;
      const int q = lchunk ^ (r & 7);
      gload16(A + ((size_t)(m0 + r) * 512 + kt * 64 + q * 8), &As[bi][rbase][0]);
      gload16(Bw + ((size_t)(n0 + r) * 512 + kt * 64 + q * 8), &Bs[bi][rbase][0]);
    }
  };

  stage(0, 0);

  for (int kt = 0; kt < 8; ++kt) {
    // top-of-iter sync: my frag-reads of (kt-1) done, my stage(kt) loads done, then all waves
    asm volatile("s_waitcnt lgkmcnt(0)" ::: "memory");
    asm volatile("s_waitcnt vmcnt(0)" ::: "memory");
    __builtin_amdgcn_s_barrier();
    if (kt < 7) stage((kt + 1) & 1, kt + 1);
    const int buf = kt & 1;
#pragma unroll
    for (int ks = 0; ks < 2; ++ks) {
      bf16x8 af[2], bfr[4];
#pragma unroll
      for (int mi = 0; mi < 2; ++mi) {
        const int row = wr * 32 + mi * 16 + l15;
        af[mi] = *(const bf16x8*)&As[buf][row][(((ks << 2) + l4) ^ (row & 7)) << 3];
      }
#pragma unroll
      for (int ni = 0; ni < 4; ++ni) {
        const int row = wc * 64 + ni * 16 + l15;
        bfr[ni] = *(const bf16x8*)&Bs[buf][row][(((ks << 2) + l4) ^ (row & 7)) << 3];
      }
#pragma unroll
      for (int mi = 0; mi < 2; ++mi)
#pragma unroll
        for (int ni = 0; ni < 4; ++ni)
          acc[mi][ni] = __builtin_amdgcn_mfma_f32_16x16x32_bf16(af[mi], bfr[ni], acc[mi][ni], 0, 0, 0);
    }
  }

#pragma unroll
  for (int ni = 0; ni < 4; ++ni) {
    const int o = n0 + wc * 64 + ni * 16 + l15;
    const float bo = bias[o];
    if (MODE == 0) {
      const int h = o / 192;
      const int jo = o - h * 192;
      const int typ = jo >> 6;  // 0=q 1=k 2=v
      const int ci = jo & 63;
#pragma unroll
      for (int mi = 0; mi < 2; ++mi) {
        const int mrow = m0 + wr * 32 + mi * 16 + l4 * 4;
        const int b = mrow >> 10, t0 = mrow & 1023;
#pragma unroll
        for (int jj = 0; jj < 4; ++jj) {
          const float v = acc[mi][ni][jj] + bo;
          const int t = t0 + jj;
          if (typ == 0)
            Qb[(((size_t)(b * 8 + h) * 1024 + t) << 6) + ci] = f2bf(v * (SCALE_QK * LOG2E));
          else if (typ == 1)
            Kb[(((size_t)(b * 8 + h) * 1024 + t) << 6) + ci] = f2bf(v * SCALE_QK);
          else
            Vb[(((size_t)(b * 8 + h) * 64 + ci) << 10) + t] = f2bf(v);
        }
      }
    } else {
#pragma unroll
      for (int mi = 0; mi < 2; ++mi) {
        const int mrow = m0 + wr * 32 + mi * 16 + l4 * 4;
        const int b = mrow >> 10, t0 = mrow & 1023;
        const size_t base = ((size_t)b * 512 + o) * 1024 + t0;
        const float4 xr = *(const float4*)(xres + base);
        float4 ov;
        ov.x = acc[mi][ni][0] + bo + xr.x;
        ov.y = acc[mi][ni][1] + bo + xr.y;
        ov.z = acc[mi][ni][2] + bo + xr.z;
        ov.w = acc[mi][ni][3] + bo + xr.w;
        *(float4*)(out + base) = ov;
      }
    }
  }
}

// ---------------- flash attention: 32x32 MFMA, swapped QK, in-register P ----------------
// 256 threads / 4 waves, 128 q-rows/block, KVBLK=64. ROTATED loop (waits at top).
__global__ __launch_bounds__(256) void k_attn(const u16* __restrict__ Qb,
                                              const u16* __restrict__ Kb,
                                              const u16* __restrict__ Vb,
                                              u16* __restrict__ ht) {
  __shared__ u16 Ks[2][64][64];   // [s][c], rswz chunk-swizzled
  __shared__ u16 Vs[2][64][64];   // [d][s], rswz chunk-swizzled
  const int tid = threadIdx.x;
  const int lane = tid & 63, wid = tid >> 6;
  const int l31 = lane & 31, hi = lane >> 5;
  const int fid = blockIdx.x;
  const int bh = fid & 127, qt = fid >> 7;
  const int b = bh >> 3, head = bh & 7;
  const int lrow = lane >> 3, lchunk = lane & 7;
  const int rsw = rswz(l31);

  bf16x8 qf[4];
  {
    const u16* qp = Qb + (((size_t)bh * 1024 + qt * 128 + wid * 32 + l31) << 6) + hi * 8;
#pragma unroll
    for (int kc = 0; kc < 4; ++kc) qf[kc] = *(const bf16x8*)(qp + kc * 16);
  }

  bf16x8 onesf;
#pragma unroll
  for (int i = 0; i < 8; ++i) onesf[i] = (l31 == 0) ? (__bf16)1.0f : (__bf16)0.0f;

  f32x16 oacc[2], osum;
#pragma unroll
  for (int r = 0; r < 16; ++r) { oacc[0][r] = 0.f; oacc[1][r] = 0.f; osum[r] = 0.f; }

  auto stageKV = [&](int bi, int st) {
    const int s0 = st * 64;
#pragma unroll
    for (int rd = 0; rd < 2; ++rd) {
      const int rbase = wid * 8 + rd * 32;
      const int r = rbase + lrow;
      const int q = lchunk ^ rswz(r);
      gload16(Kb + (((size_t)bh * 1024 + s0 + r) << 6) + q * 8, &Ks[bi][rbase][0]);
      gload16(Vb + (((size_t)bh * 64 + r) << 10) + s0 + q * 8, &Vs[bi][rbase][0]);
    }
  };

  stageKV(0, 0);

  for (int st = 0; st < 16; ++st) {
    asm volatile("s_waitcnt lgkmcnt(0)" ::: "memory");
    asm volatile("s_waitcnt vmcnt(0)" ::: "memory");
    __builtin_amdgcn_s_barrier();
    if (st < 15) stageKV((st + 1) & 1, st + 1);
    const int buf = st & 1;

#pragma unroll
    for (int cb = 0; cb < 2; ++cb) {
      f32x16 sacc;
#pragma unroll
      for (int r = 0; r < 16; ++r) sacc[r] = 0.f;
      __builtin_amdgcn_s_setprio(1);
#pragma unroll
      for (int kc = 0; kc < 4; ++kc) {
        const int r = cb * 32 + l31;
        const bf16x8 kb = *(const bf16x8*)&Ks[buf][r][((((kc << 1) | hi)) ^ rsw) << 3];
        sacc = __builtin_amdgcn_mfma_f32_32x32x16_bf16(kb, qf[kc], sacc, 0, 0, 0);
      }
      __builtin_amdgcn_s_setprio(0);
      float p[16];
#pragma unroll
      for (int r = 0; r < 16; ++r)
        asm("v_exp_f32 %0, %1" : "=v"(p[r]) : "v"(sacc[r]));

#pragma unroll
      for (int ksl = 0; ksl < 2; ++ksl) {
        u32 X0, X1, Y0, Y1;
        asm("v_cvt_pk_bf16_f32 %0, %1, %2" : "=v"(X0) : "v"(p[8 * ksl + 0]), "v"(p[8 * ksl + 1]));
        asm("v_cvt_pk_bf16_f32 %0, %1, %2" : "=v"(X1) : "v"(p[8 * ksl + 2]), "v"(p[8 * ksl + 3]));
        asm("v_cvt_pk_bf16_f32 %0, %1, %2" : "=v"(Y0) : "v"(p[8 * ksl + 4]), "v"(p[8 * ksl + 5]));
        asm("v_cvt_pk_bf16_f32 %0, %1, %2" : "=v"(Y1) : "v"(p[8 * ksl + 6]), "v"(p[8 * ksl + 7]));
        asm volatile("v_permlane32_swap_b32 %0, %1" : "+v"(X0), "+v"(Y0));
        asm volatile("v_permlane32_swap_b32 %0, %1" : "+v"(X1), "+v"(Y1));
        union { u32 w[4]; bf16x8 v; } pa;
        pa.w[0] = X0; pa.w[1] = X1; pa.w[2] = Y0; pa.w[3] = Y1;
        const int ks = cb * 2 + ksl;
        __builtin_amdgcn_s_setprio(1);
#pragma unroll
        for (int db = 0; db < 2; ++db) {
          const int r = db * 32 + l31;
          const bf16x8 vb = *(const bf16x8*)&Vs[buf][r][((((ks << 1) | hi)) ^ rsw) << 3];
          oacc[db] = __builtin_amdgcn_mfma_f32_32x32x16_bf16(pa.v, vb, oacc[db], 0, 0, 0);
        }
        osum = __builtin_amdgcn_mfma_f32_32x32x16_bf16(pa.v, onesf, osum, 0, 0, 0);
        __builtin_amdgcn_s_setprio(0);
      }
    }
  }

  float inv[16];
#pragma unroll
  for (int r = 0; r < 16; ++r) {
    const float ls = __shfl(osum[r], lane & 32);
    inv[r] = 1.f / ls;
  }
#pragma unroll
  for (int db = 0; db < 2; ++db) {
#pragma unroll
    for (int r = 0; r < 16; ++r) {
      const int t = qt * 128 + wid * 32 + (r & 3) + 8 * (r >> 2) + 4 * hi;
      const int cg = head * 64 + db * 32 + l31;
      ht[((size_t)b * 1024 + t) * 512 + cg] = f2bf(oacc[db][r] * inv[r]);
    }
  }
}

extern "C" void kernel_launch(void* const* d_in, const int* in_sizes, int n_in,
                              void* d_out, int out_size, void* d_ws, size_t ws_size,
                              hipStream_t stream) {
  const float* x = (const float*)d_in[0];
  const float* norm_w = (const float*)d_in[1];
  const float* norm_b = (const float*)d_in[2];
  const float* qkv_w = (const float*)d_in[3];
  const float* qkv_b = (const float*)d_in[4];
  const float* proj_w = (const float*)d_in[5];
  const float* proj_b = (const float*)d_in[6];
  float* out = (float*)d_out;

  char* ws = (char*)d_ws;
  u16* qkvw = (u16*)(ws + 0);          // 1,572,864 B
  u16* projw = (u16*)(ws + 1572864);   //   524,288 B
  u16* gnt = (u16*)(ws + 2097152);     // 16,777,216 B  gn_t[b][t][c]
  u16* Qb = (u16*)(ws + 18874368);     // 16,777,216 B  Q[bh][t][ci]
  u16* Kb = (u16*)(ws + 35651584);     // 16,777,216 B  K[bh][s][ci]
  u16* Vb = (u16*)(ws + 52428800);     // 16,777,216 B  V[bh][ci][s]
  u16* ht = (u16*)(ws + 69206016);     // 16,777,216 B  h_t[b][t][c]

  k_convert<<<768, 256, 0, stream>>>(qkv_w, qkvw, 196608);
  k_convert<<<256, 256, 0, stream>>>(proj_w, projw, 65536);
  k_groupnorm<<<512, 256, 0, stream>>>(x, norm_w, norm_b, gnt);
  k_gemm<0><<<1536, 512, 0, stream>>>(gnt, qkvw, qkv_b, Qb, Kb, Vb, nullptr, nullptr);
  k_attn<<<1024, 256, 0, stream>>>(Qb, Kb, Vb, ht);
  k_gemm<1><<<512, 512, 0, stream>>>(ht, projw, proj_b, nullptr, nullptr, nullptr, x, out);
}